// Round 22
// baseline (79.466 us; speedup 1.0000x reference)
//
#include <hip/hip_runtime.h>
#include <hip/hip_bf16.h>

#define NUM_EMB 1024
#define EMB_DIM 64
#define NPIX    131072                 // 32*64*64 pixels
#define ZQ_ELEMS 8388608               // NPIX * EMB_DIM
#define KDEPTH  16
#define ZSTRIDE 65                     // padded f32 LDS stride (conflict-free)
#define NACC    64                     // spread loss accumulators
#define BIAS    0.25f                  // makes screen scores positive (packable)
#define PXB     128                    // pixels per block
#define NPG     8                      // pixel-groups per wave

// d_out FLOAT32: [ z_q (8388608, b-c-h-w) | loss (1) | enc (131072) ]
// d_ws: [ E'frag 128KB | e2 4KB @131072 | e2+BIAS 4KB @135168 | lossAcc @139264 ]

typedef __attribute__((ext_vector_type(8))) short short8_t;  // bf16x8 frag
typedef __attribute__((ext_vector_type(4))) float f32x4;     // mfma acc

__device__ __forceinline__ unsigned umin32(unsigned a, unsigned b) { return a < b ? a : b; }
__device__ __forceinline__ unsigned umed3(unsigned a, unsigned b, unsigned c) {
    unsigned r;
    asm("v_med3_u32 %0, %1, %2, %3" : "=v"(r) : "v"(a), "v"(b), "v"(c));
    return r;
}

// numpy pairwise-sum (n=64, 8-accumulator) of x[j]^2 — token-identical to the
// round-5..21 PASSING kernels (bit-matches np.sum(x**2, axis=-1)).
__device__ __forceinline__ float np_sumsq64(const float* __restrict__ x) {
    float q[EMB_DIM];
    #pragma unroll
    for (int c = 0; c < EMB_DIM; ++c) q[c] = x[c] * x[c];
    float r0 = q[0], r1 = q[1], r2 = q[2], r3 = q[3];
    float r4 = q[4], r5 = q[5], r6 = q[6], r7 = q[7];
    #pragma unroll
    for (int g = 1; g < 8; ++g) {
        r0 += q[8 * g + 0]; r1 += q[8 * g + 1];
        r2 += q[8 * g + 2]; r3 += q[8 * g + 3];
        r4 += q[8 * g + 4]; r5 += q[8 * g + 5];
        r6 += q[8 * g + 6]; r7 += q[8 * g + 7];
    }
    return ((r0 + r1) + (r2 + r3)) + ((r4 + r5) + (r6 + r7));
}

__device__ __forceinline__ unsigned long long packvk(float v, int k) {
    unsigned u = __float_as_uint(v);
    u = (u & 0x80000000u) ? ~u : (u | 0x80000000u);   // monotonic f32 -> u32
    return ((unsigned long long)u << 32) | (unsigned)k;
}

// Exact np-f32 candidate score: sequential fmaf chain (BLAS order), float4 loads.
__device__ __forceinline__ float np_score(const float* __restrict__ emb, int k,
                                          const float* __restrict__ zl,
                                          float zzv, float e2k) {
    const float4* ek4 = (const float4*)(emb + k * EMB_DIM);
    float acc = 0.f;
    #pragma unroll
    for (int c4 = 0; c4 < 16; ++c4) {
        float4 e4 = ek4[c4];
        acc = fmaf(e4.x, zl[c4 * 4 + 0], acc);
        acc = fmaf(e4.y, zl[c4 * 4 + 1], acc);
        acc = fmaf(e4.z, zl[c4 * 4 + 2], acc);
        acc = fmaf(e4.w, zl[c4 * 4 + 3], acc);
    }
    return (zzv + e2k) - 2.0f * acc;               // exact np token sequence
}

// Prep (32 blocks): one E'frag half per thread + np-exact e2 (+biased copy).
__global__ __launch_bounds__(256) void vq_prep(const float* __restrict__ emb,
                                               short* __restrict__ wsE,
                                               float* __restrict__ wsE2,
                                               float* __restrict__ wsE2b,
                                               float* __restrict__ wsAcc) {
    #pragma clang fp contract(off)
    int t = blockIdx.x * 256 + threadIdx.x;       // grid = 32 x 256 = 8192
    if (blockIdx.x == 0 && threadIdx.x < NACC) wsAcc[threadIdx.x] = 0.f;
    int tt   = t >> 1;                            // frag triple 0..4095
    int h    = t & 1;                             // half 0/1
    int l    = tt & 63;
    int ch   = (tt >> 6) & 15;
    int q    = tt >> 10;
    int code = q * 256 + ch * 16 + (l & 15);
    const float* ek = emb + code * EMB_DIM;
    short8_t pk;
    #pragma unroll
    for (int j = 0; j < 8; ++j) {
        int chan = 32 * h + 8 * (l >> 4) + j;
        __hip_bfloat16 bv = __float2bfloat16(-2.0f * ek[chan]);
        unsigned short u; __builtin_memcpy(&u, &bv, 2);
        pk[j] = (short)u;
    }
    *(short8_t*)(wsE + tt * 16 + h * 8) = pk;
    if (t < NUM_EMB) {
        float e2 = np_sumsq64(emb + t * EMB_DIM);
        wsE2[t]  = e2;
        wsE2b[t] = e2 + BIAS;                     // same f32 add as before
    }
}

// ---------------------------------------------------------------------------
// Main: r21 structure, LDS dieted to ~40KB -> 4 blocks/CU -> grid (1024) is
// exactly ONE generation (no tail). e2 tables read from global (L1-hot);
// cross-wave min via LDS atomicMin (packed domain); zz recomputed in eval.
// ---------------------------------------------------------------------------
__global__ __launch_bounds__(256, 4) void vq_mfma(const float* __restrict__ z_e,
                                                  const float* __restrict__ emb,
                                                  const short* __restrict__ wsE,
                                                  const float* __restrict__ wsE2,
                                                  const float* __restrict__ wsE2b,
                                                  float* __restrict__ zq_out,
                                                  float* __restrict__ enc_out,
                                                  float* __restrict__ wsAcc) {
    #pragma clang fp contract(off)
    __shared__ float sZf[PXB * ZSTRIDE];          // 33.3 KB exact f32 z tile
    __shared__ unsigned sMinP[PXB];               // 0.5 KB packed global min
    __shared__ float sThr[PXB];                   // band, then thrF in place
    __shared__ unsigned long long sBestPack[PXB]; // 1 KB (mono(v)<<32)|k
    __shared__ unsigned short sKbuf[PXB][KDEPTH]; // 4 KB
    __shared__ int   sKcnt[PXB];                  // 0.5 KB
    __shared__ unsigned short sPxFlag[PXB];       // 0.25 KB
    __shared__ int   sFlagAny;

    const int tid  = threadIdx.x;
    const int w    = tid >> 6;
    const int lane = tid & 63;
    const int p0   = blockIdx.x * PXB;
    const int b    = p0 >> 12;                    // uniform (128 | 4096)
    const int hw0  = p0 & 4095;
    const float* base = z_e + (size_t)b * (EMB_DIM * 4096) + hw0;

    if (tid < PXB) {
        sKcnt[tid] = 0; sBestPack[tid] = ~0ULL; sPxFlag[tid] = 0;
        sMinP[tid] = ~0u;
    }
    if (tid == 0) sFlagAny = 0;

    // --- tile load: 2 threads/pixel, 32 channels each (coalesced) ---
    {
        const int px = tid & (PXB - 1);
        const int cg = tid >> 7;                  // channel half 0/1
        const float* zp = base + px;
        float v[32];
        #pragma unroll
        for (int j = 0; j < 32; ++j) v[j] = zp[(size_t)(32 * cg + j) * 4096];
        #pragma unroll
        for (int j = 0; j < 32; ++j) sZf[px * ZSTRIDE + 32 * cg + j] = v[j];
    }
    __syncthreads();                               // B1

    // --- waves 0-1: band per pixel (zz recomputed later in eval) ---
    if (tid < PXB) {
        const float* zl = &sZf[tid * ZSTRIDE];
        float sab = 0.f;
        #pragma unroll
        for (int c = 0; c < EMB_DIM; ++c) sab += fabsf(zl[c]);
        // band guard: +1e-4 covers packed 10-bit mantissa quantization
        sThr[tid] = 2.0f * (9e-6f * sab + 2e-5f) + 1e-4f;
    }

    // --- B fragments (8 pixel-groups) from f32 LDS, PINNED in VGPRs ---
    short8_t bfrag[NPG][2];
    #pragma unroll
    for (int pg = 0; pg < NPG; ++pg)
        #pragma unroll
        for (int h = 0; h < 2; ++h) {
            int bpr = pg * 16 + (lane & 15);
            int c0  = 32 * h + 8 * (lane >> 4);
            short8_t pk;
            #pragma unroll
            for (int j = 0; j < 8; ++j) {
                __hip_bfloat16 bv = __float2bfloat16(sZf[bpr * ZSTRIDE + c0 + j]);
                unsigned short u; __builtin_memcpy(&u, &bv, 2);
                pk[j] = (short)u;
            }
            asm volatile("" : "+v"(pk));          // force materialization
            bfrag[pg][h] = pk;
        }

    const short8_t* ef = (const short8_t*)wsE + (size_t)w * 2048;

    // ===== SINGLE SCREEN PASS: packed u32 top-3 (med3 insert); 2-deep PF =====
    unsigned p1[NPG], p2[NPG], p3[NPG];
    #pragma unroll
    for (int pg = 0; pg < NPG; ++pg) { p1[pg] = ~0u; p2[pg] = ~0u; p3[pg] = ~0u; }
    {
        short8_t A0a = ef[(0 * 64 + lane) * 2 + 0];
        short8_t A1a = ef[(0 * 64 + lane) * 2 + 1];
        short8_t A0b = ef[(1 * 64 + lane) * 2 + 0];
        short8_t A1b = ef[(1 * 64 + lane) * 2 + 1];
        #pragma unroll 1
        for (int ch = 0; ch < 16; ch += 2) {
            {   // even: consumes (A0a,A1a), prefetches ch+2
                int chn = ch + 2 < 16 ? ch + 2 : 15;
                short8_t N0 = ef[(chn * 64 + lane) * 2 + 0];
                short8_t N1 = ef[(chn * 64 + lane) * 2 + 1];
                int kbase = w * 256 + ch * 16 + 4 * (lane >> 4);
                f32x4 e2bv = *(const f32x4*)(wsE2b + kbase);   // L1-hot
                unsigned kb[4] = {(unsigned)kbase, (unsigned)kbase + 1u,
                                  (unsigned)kbase + 2u, (unsigned)kbase + 3u};
                #pragma unroll
                for (int pg = 0; pg < NPG; ++pg) {
                    f32x4 acc = __builtin_amdgcn_mfma_f32_16x16x32_bf16(A0a, bfrag[pg][0], e2bv, 0, 0, 0);
                    acc = __builtin_amdgcn_mfma_f32_16x16x32_bf16(A1a, bfrag[pg][1], acc, 0, 0, 0);
                    #pragma unroll
                    for (int j = 0; j < 4; ++j) {
                        unsigned t   = (__float_as_uint(acc[j]) & 0xFFFFFC00u) | kb[j];
                        unsigned np2 = umed3(p1[pg], p2[pg], t);
                        unsigned np3 = umed3(p2[pg], p3[pg], t);
                        p1[pg] = umin32(p1[pg], t);
                        p2[pg] = np2; p3[pg] = np3;
                    }
                }
                A0a = N0; A1a = N1;
            }
            {   // odd: consumes (A0b,A1b), prefetches ch+3
                int chn = ch + 3 < 16 ? ch + 3 : 15;
                short8_t N0 = ef[(chn * 64 + lane) * 2 + 0];
                short8_t N1 = ef[(chn * 64 + lane) * 2 + 1];
                int kbase = w * 256 + (ch + 1) * 16 + 4 * (lane >> 4);
                f32x4 e2bv = *(const f32x4*)(wsE2b + kbase);
                unsigned kb[4] = {(unsigned)kbase, (unsigned)kbase + 1u,
                                  (unsigned)kbase + 2u, (unsigned)kbase + 3u};
                #pragma unroll
                for (int pg = 0; pg < NPG; ++pg) {
                    f32x4 acc = __builtin_amdgcn_mfma_f32_16x16x32_bf16(A0b, bfrag[pg][0], e2bv, 0, 0, 0);
                    acc = __builtin_amdgcn_mfma_f32_16x16x32_bf16(A1b, bfrag[pg][1], acc, 0, 0, 0);
                    #pragma unroll
                    for (int j = 0; j < 4; ++j) {
                        unsigned t   = (__float_as_uint(acc[j]) & 0xFFFFFC00u) | kb[j];
                        unsigned np2 = umed3(p1[pg], p2[pg], t);
                        unsigned np3 = umed3(p2[pg], p3[pg], t);
                        p1[pg] = umin32(p1[pg], t);
                        p2[pg] = np2; p3[pg] = np3;
                    }
                }
                A0b = N0; A1b = N1;
            }
        }
    }

    // per-pixel global packed min: shfl within wave, atomicMin across waves
    #pragma unroll
    for (int pg = 0; pg < NPG; ++pg) {
        unsigned g = p1[pg];
        g = umin32(g, (unsigned)__shfl_xor((int)g, 16, 64));
        g = umin32(g, (unsigned)__shfl_xor((int)g, 32, 64));
        if (lane < 16) atomicMin(&sMinP[pg * 16 + lane], g);
    }
    __syncthreads();                               // B2
    if (tid < PXB) {
        float m = __uint_as_float(sMinP[tid] & 0xFFFFFC00u);
        sThr[tid] = m + sThr[tid];                 // band -> thrF in place
    }
    __syncthreads();                               // B3

    // ===== EMIT: single atomic per (lane,pg); flag on p3 in band =====
    #pragma unroll
    for (int pg = 0; pg < NPG; ++pg) {
        int px = pg * 16 + (lane & 15);
        unsigned thrp = (__float_as_uint(sThr[px]) & 0xFFFFFC00u) | 1023u;
        int n = (p1[pg] <= thrp) + (p2[pg] <= thrp) + (p3[pg] <= thrp);
        if (n) {
            int slot = atomicAdd(&sKcnt[px], n);
            if (slot < KDEPTH)                     sKbuf[px][slot]     = (unsigned short)(p1[pg] & 1023u);
            if (n >= 2 && slot + 1 < KDEPTH)       sKbuf[px][slot + 1] = (unsigned short)(p2[pg] & 1023u);
            if (n >= 3) {
                if (slot + 2 < KDEPTH)             sKbuf[px][slot + 2] = (unsigned short)(p3[pg] & 1023u);
                sPxFlag[px] = 1; sFlagAny = 1;     // lane may have dropped a 4th
            }
        }
    }
    __syncthreads();                               // B4

    // ===== RARE: flagged pixels -> full recollect (8 pg, 1-deep prefetch) =====
    if (sFlagAny) {
        if (tid < PXB && sPxFlag[tid]) sKcnt[tid] = 0;
        __syncthreads();
        float thrB[NPG];
        #pragma unroll
        for (int pg = 0; pg < NPG; ++pg) {
            int px = pg * 16 + (lane & 15);
            thrB[pg] = sPxFlag[px] ? sThr[px] : -1e30f;
        }
        short8_t A0 = ef[lane * 2 + 0];
        short8_t A1 = ef[lane * 2 + 1];
        #pragma unroll 1
        for (int ch = 0; ch < 16; ++ch) {
            int chn = ch < 15 ? ch + 1 : 15;
            short8_t N0 = ef[(chn * 64 + lane) * 2 + 0];
            short8_t N1 = ef[(chn * 64 + lane) * 2 + 1];
            int kbase = w * 256 + ch * 16 + 4 * (lane >> 4);
            f32x4 e2bv = *(const f32x4*)(wsE2b + kbase);
            #pragma unroll
            for (int pg = 0; pg < NPG; ++pg) {
                f32x4 acc = __builtin_amdgcn_mfma_f32_16x16x32_bf16(A0, bfrag[pg][0], e2bv, 0, 0, 0);
                acc = __builtin_amdgcn_mfma_f32_16x16x32_bf16(A1, bfrag[pg][1], acc, 0, 0, 0);
                #pragma unroll
                for (int j = 0; j < 4; ++j) {
                    if (acc[j] <= thrB[pg]) {
                        int pix  = pg * 16 + (lane & 15);
                        int slot = atomicAdd(&sKcnt[pix], 1);
                        if (slot < KDEPTH) sKbuf[pix][slot] = (unsigned short)(kbase + j);
                    }
                }
            }
            A0 = N0; A1 = N1;
        }
        __syncthreads();
    }

    // ===== EXACT EVAL: 2 threads/pixel; rawcnt==1 certified shortcut =====
    {
        const int px   = tid & (PXB - 1);
        const int half = tid >> 7;
        const float* zl = &sZf[px * ZSTRIDE];
        int rawcnt = sKcnt[px];
        if (rawcnt == 1) {
            if (half == 0) sBestPack[px] = packvk(-1e30f, (int)sKbuf[px][0]);
        } else if (rawcnt <= KDEPTH) {
            float zzv = np_sumsq64(zl);            // canonical np order (bit-same)
            for (int s = half; s < rawcnt; s += 2) {
                int k = (int)sKbuf[px][s];
                float v = np_score(emb, k, zl, zzv, wsE2[k]);
                atomicMin(&sBestPack[px], packvk(v, k));
            }
        } else {                                   // overflow safety net (~never)
            float zzv = np_sumsq64(zl);
            for (int k = half; k < NUM_EMB; k += 2) {
                float v = np_score(emb, k, zl, zzv, wsE2[k]);
                atomicMin(&sBestPack[px], packvk(v, k));
            }
        }
    }
    __syncthreads();

    // ===== enc + epilogue (2 threads/pixel, 32 ch each, float4 gather) =====
    if (tid < PXB)
        enc_out[p0 + tid] = (float)(unsigned)(sBestPack[tid] & 0xFFFFFFFFull);
    {
        const int px   = tid & (PXB - 1);
        const int cg   = tid >> 7;
        int bestk = (int)(sBestPack[px] & 0xFFFFFFFFull);
        const float4* eq4 = (const float4*)(emb + bestk * EMB_DIM) + 8 * cg;
        const float* zl = &sZf[px * ZSTRIDE];
        float* op = zq_out + (size_t)b * (EMB_DIM * 4096) + hw0 + px;
        float ls = 0.f;
        #pragma unroll
        for (int j4 = 0; j4 < 8; ++j4) {
            float4 e4 = eq4[j4];
            int c = 32 * cg + j4 * 4;
            float d0 = e4.x - zl[c + 0];
            float d1 = e4.y - zl[c + 1];
            float d2 = e4.z - zl[c + 2];
            float d3 = e4.w - zl[c + 3];
            ls = fmaf(d0, d0, ls);
            ls = fmaf(d1, d1, ls);
            ls = fmaf(d2, d2, ls);
            ls = fmaf(d3, d3, ls);
            op[(size_t)(c + 0) * 4096] = e4.x;
            op[(size_t)(c + 1) * 4096] = e4.y;
            op[(size_t)(c + 2) * 4096] = e4.z;
            op[(size_t)(c + 3) * 4096] = e4.w;
        }
        #pragma unroll
        for (int off = 32; off > 0; off >>= 1) ls += __shfl_down(ls, off, 64);
        if (lane == 0) atomicAdd(&wsAcc[blockIdx.x & (NACC - 1)], ls);
    }
}

__global__ void vq_final_ws(const float* __restrict__ wsAcc,
                            float* __restrict__ loss_out) {
    int lane = threadIdx.x;                       // 64 threads
    float v = wsAcc[lane];
    #pragma unroll
    for (int off = 32; off > 0; off >>= 1) v += __shfl_down(v, off, 64);
    if (lane == 0) loss_out[0] = v * (1.25f / (float)ZQ_ELEMS);
}

__global__ void vq_final_direct(float* __restrict__ loss_out) {
    loss_out[0] = loss_out[0] * (1.25f / (float)ZQ_ELEMS);
}

// ---------- fallback (round-6 passing kernel) if d_ws is too small ----------
__global__ __launch_bounds__(256) void vq_nn_fb(const float* __restrict__ z_e,
                                                const float* __restrict__ emb,
                                                float* __restrict__ zq_out,
                                                float* __restrict__ enc_out,
                                                float* __restrict__ loss_acc) {
    #pragma clang fp contract(off)
    __shared__ float s_e2[NUM_EMB];
    int tid = threadIdx.x;
    for (int k = tid; k < NUM_EMB; k += 256) s_e2[k] = np_sumsq64(emb + k * EMB_DIM);
    __syncthreads();
    int p = blockIdx.x * 256 + tid;
    int b = p >> 12, hw = p & 4095;
    const float* zp = z_e + (size_t)b * (EMB_DIM * 4096) + hw;
    float z[EMB_DIM];
    #pragma unroll
    for (int c = 0; c < EMB_DIM; ++c) z[c] = zp[(size_t)c * 4096];
    float zz = np_sumsq64(z);
    float b1 = 3.4e38f; int i1 = 0;
    #pragma unroll 2
    for (int k = 0; k < NUM_EMB; ++k) {
        const float* ek = emb + k * EMB_DIM;
        float acc = 0.f;
        #pragma unroll
        for (int c = 0; c < EMB_DIM; ++c) acc = fmaf(ek[c], z[c], acc);
        float sc = (zz + s_e2[k]) - 2.0f * acc;
        bool lt = sc < b1; b1 = lt ? sc : b1; i1 = lt ? k : i1;
    }
    const float* eq = emb + i1 * EMB_DIM;
    float* op = zq_out + (size_t)b * (EMB_DIM * 4096) + hw;
    float ls = 0.f;
    #pragma unroll
    for (int c = 0; c < EMB_DIM; ++c) {
        float q = eq[c]; float d = q - z[c];
        ls = fmaf(d, d, ls);
        op[(size_t)c * 4096] = q;
    }
    enc_out[p] = (float)i1;
    #pragma unroll
    for (int off = 32; off > 0; off >>= 1) ls += __shfl_down(ls, off, 64);
    if ((tid & 63) == 0) atomicAdd(loss_acc, ls);
}

extern "C" void kernel_launch(void* const* d_in, const int* in_sizes, int n_in,
                              void* d_out, int out_size, void* d_ws, size_t ws_size,
                              hipStream_t stream) {
    const float* z_e = (const float*)d_in[0];
    const float* emb = (const float*)d_in[1];
    float* out = (float*)d_out;
    float* loss_out = out + ZQ_ELEMS;
    float* enc_out  = out + ZQ_ELEMS + 1;

    if (ws_size >= 140 * 1024) {
        short* wsE   = (short*)d_ws;                       // 128 KB frag-order
        float* wsE2  = (float*)((char*)d_ws + 131072);     // 4 KB unbiased
        float* wsE2b = (float*)((char*)d_ws + 135168);     // 4 KB biased
        float* wsAcc = (float*)((char*)d_ws + 139264);     // 256 B
        vq_prep<<<32, 256, 0, stream>>>(emb, wsE, wsE2, wsE2b, wsAcc);
        vq_mfma<<<NPIX / PXB, 256, 0, stream>>>(z_e, emb, wsE, wsE2, wsE2b,
                                                out, enc_out, wsAcc);
        vq_final_ws<<<1, 64, 0, stream>>>(wsAcc, loss_out);
    } else {
        hipMemsetAsync(loss_out, 0, 4, stream);
        vq_nn_fb<<<NPIX / 256, 256, 0, stream>>>(z_e, emb, out, enc_out, loss_out);
        vq_final_direct<<<1, 1, 0, stream>>>(loss_out);
    }
}

// Round 23
// 76.392 us; speedup vs baseline: 1.0402x; 1.0402x over previous
//
#include <hip/hip_runtime.h>
#include <hip/hip_bf16.h>

#define NUM_EMB 1024
#define EMB_DIM 64
#define NPIX    131072                 // 32*64*64 pixels
#define ZQ_ELEMS 8388608               // NPIX * EMB_DIM
#define KDEPTH  16
#define ZSTRIDE 65                     // padded f32 LDS stride (conflict-free)
#define NACC    64                     // spread loss accumulators
#define BIAS    0.25f                  // makes screen scores positive (packable)
#define PXB     128                    // pixels per block
#define NPG     8                      // pixel-groups per wave

// d_out FLOAT32: [ z_q (8388608, b-c-h-w) | loss (1) | enc (131072) ]
// d_ws: [ E'frag 128KB | e2 f32 4KB | lossAcc f32[64] @135168 ]

typedef __attribute__((ext_vector_type(8))) short short8_t;  // bf16x8 frag
typedef __attribute__((ext_vector_type(4))) float f32x4;     // mfma acc

__device__ __forceinline__ unsigned umin32(unsigned a, unsigned b) { return a < b ? a : b; }
__device__ __forceinline__ unsigned umed3(unsigned a, unsigned b, unsigned c) {
    unsigned r;
    asm("v_med3_u32 %0, %1, %2, %3" : "=v"(r) : "v"(a), "v"(b), "v"(c));
    return r;
}

// numpy pairwise-sum (n=64, 8-accumulator) of x[j]^2 — token-identical to the
// round-5..21 PASSING kernels (bit-matches np.sum(x**2, axis=-1)).
__device__ __forceinline__ float np_sumsq64(const float* __restrict__ x) {
    float q[EMB_DIM];
    #pragma unroll
    for (int c = 0; c < EMB_DIM; ++c) q[c] = x[c] * x[c];
    float r0 = q[0], r1 = q[1], r2 = q[2], r3 = q[3];
    float r4 = q[4], r5 = q[5], r6 = q[6], r7 = q[7];
    #pragma unroll
    for (int g = 1; g < 8; ++g) {
        r0 += q[8 * g + 0]; r1 += q[8 * g + 1];
        r2 += q[8 * g + 2]; r3 += q[8 * g + 3];
        r4 += q[8 * g + 4]; r5 += q[8 * g + 5];
        r6 += q[8 * g + 6]; r7 += q[8 * g + 7];
    }
    return ((r0 + r1) + (r2 + r3)) + ((r4 + r5) + (r6 + r7));
}

__device__ __forceinline__ unsigned long long packvk(float v, int k) {
    unsigned u = __float_as_uint(v);
    u = (u & 0x80000000u) ? ~u : (u | 0x80000000u);   // monotonic f32 -> u32
    return ((unsigned long long)u << 32) | (unsigned)k;
}

// Exact np-f32 candidate score: sequential fmaf chain (BLAS order), float4 loads.
__device__ __forceinline__ float np_score(const float* __restrict__ emb, int k,
                                          const float* __restrict__ zl,
                                          float zzv, float e2k) {
    const float4* ek4 = (const float4*)(emb + k * EMB_DIM);
    float acc = 0.f;
    #pragma unroll
    for (int c4 = 0; c4 < 16; ++c4) {
        float4 e4 = ek4[c4];
        acc = fmaf(e4.x, zl[c4 * 4 + 0], acc);
        acc = fmaf(e4.y, zl[c4 * 4 + 1], acc);
        acc = fmaf(e4.z, zl[c4 * 4 + 2], acc);
        acc = fmaf(e4.w, zl[c4 * 4 + 3], acc);
    }
    return (zzv + e2k) - 2.0f * acc;               // exact np token sequence
}

// Prep (32 blocks): one E'frag half per thread + np-exact e2.
__global__ __launch_bounds__(256) void vq_prep(const float* __restrict__ emb,
                                               short* __restrict__ wsE,
                                               float* __restrict__ wsE2,
                                               float* __restrict__ wsAcc) {
    #pragma clang fp contract(off)
    int t = blockIdx.x * 256 + threadIdx.x;       // grid = 32 x 256 = 8192
    if (blockIdx.x == 0 && threadIdx.x < NACC) wsAcc[threadIdx.x] = 0.f;
    int tt   = t >> 1;                            // frag triple 0..4095
    int h    = t & 1;                             // half 0/1
    int l    = tt & 63;
    int ch   = (tt >> 6) & 15;
    int q    = tt >> 10;
    int code = q * 256 + ch * 16 + (l & 15);
    const float* ek = emb + code * EMB_DIM;
    short8_t pk;
    #pragma unroll
    for (int j = 0; j < 8; ++j) {
        int chan = 32 * h + 8 * (l >> 4) + j;
        __hip_bfloat16 bv = __float2bfloat16(-2.0f * ek[chan]);
        unsigned short u; __builtin_memcpy(&u, &bv, 2);
        pk[j] = (short)u;
    }
    *(short8_t*)(wsE + tt * 16 + h * 8) = pk;
    if (t < NUM_EMB) wsE2[t] = np_sumsq64(emb + t * EMB_DIM);
}

// ---------------------------------------------------------------------------
// Main (round-21 best): 128 px/block, single MFMA screen pass with packed u32
// top-3 (med3 insert), flag->rare recollect, exact np-f32 eval on candidates,
// float4 eval/epilogue loads. Final configuration.
// ---------------------------------------------------------------------------
__global__ __launch_bounds__(256, 3) void vq_mfma(const float* __restrict__ z_e,
                                                  const float* __restrict__ emb,
                                                  const short* __restrict__ wsE,
                                                  const float* __restrict__ wsE2,
                                                  float* __restrict__ zq_out,
                                                  float* __restrict__ enc_out,
                                                  float* __restrict__ wsAcc) {
    #pragma clang fp contract(off)
    __shared__ float sZf[PXB * ZSTRIDE];          // 33.3 KB exact f32 z tile
    __shared__ float sE2[NUM_EMB];                // 4 KB (unbiased)
    __shared__ unsigned sMinP[4][PXB];            // 2 KB packed wave mins
    __shared__ float sBand[PXB];
    __shared__ float sThrF[PXB];
    __shared__ unsigned sThrP[PXB];
    __shared__ float sZZ[PXB];
    __shared__ unsigned long long sBestPack[PXB]; // (mono(v)<<32)|k
    __shared__ unsigned short sKbuf[PXB][KDEPTH]; // 4 KB
    __shared__ int   sKcnt[PXB];
    __shared__ int   sPxFlag[PXB];
    __shared__ int   sFlagAny;

    const int tid  = threadIdx.x;
    const int w    = tid >> 6;
    const int lane = tid & 63;
    const int p0   = blockIdx.x * PXB;
    const int b    = p0 >> 12;                    // uniform (128 | 4096)
    const int hw0  = p0 & 4095;
    const float* base = z_e + (size_t)b * (EMB_DIM * 4096) + hw0;

    *(f32x4*)&sE2[tid * 4] = *(const f32x4*)&wsE2[tid * 4];
    if (tid < PXB) { sKcnt[tid] = 0; sBestPack[tid] = ~0ULL; sPxFlag[tid] = 0; }
    if (tid == 0) sFlagAny = 0;

    // --- tile load: 2 threads/pixel, 32 channels each (coalesced) ---
    {
        const int px = tid & (PXB - 1);
        const int cg = tid >> 7;                  // channel half 0/1
        const float* zp = base + px;
        float v[32];
        #pragma unroll
        for (int j = 0; j < 32; ++j) v[j] = zp[(size_t)(32 * cg + j) * 4096];
        #pragma unroll
        for (int j = 0; j < 32; ++j) sZf[px * ZSTRIDE + 32 * cg + j] = v[j];
    }
    __syncthreads();                               // B1

    // --- waves 0-1: np-exact zz + band (overlaps waves 2-3 bfrag/screen) ---
    if (tid < PXB) {
        const float* zl = &sZf[tid * ZSTRIDE];
        float rr[8] = {0,0,0,0,0,0,0,0};
        float sab = 0.f;
        #pragma unroll
        for (int g = 0; g < 8; ++g)
            #pragma unroll
            for (int j = 0; j < 8; ++j) {
                float zc = zl[8 * g + j];
                float qq = zc * zc;               // separate mul (contract off)
                rr[j] += qq;                      // g-ascending per j = np order
                sab += fabsf(zc);
            }
        sZZ[tid]   = ((rr[0] + rr[1]) + (rr[2] + rr[3])) + ((rr[4] + rr[5]) + (rr[6] + rr[7]));
        // band guard: +1e-4 covers packed 10-bit mantissa quantization
        sBand[tid] = 2.0f * (9e-6f * sab + 2e-5f) + 1e-4f;
    }

    // --- B fragments (8 pixel-groups) from f32 LDS, PINNED in VGPRs ---
    short8_t bfrag[NPG][2];
    #pragma unroll
    for (int pg = 0; pg < NPG; ++pg)
        #pragma unroll
        for (int h = 0; h < 2; ++h) {
            int bpr = pg * 16 + (lane & 15);
            int c0  = 32 * h + 8 * (lane >> 4);
            short8_t pk;
            #pragma unroll
            for (int j = 0; j < 8; ++j) {
                __hip_bfloat16 bv = __float2bfloat16(sZf[bpr * ZSTRIDE + c0 + j]);
                unsigned short u; __builtin_memcpy(&u, &bv, 2);
                pk[j] = (short)u;
            }
            asm volatile("" : "+v"(pk));          // force materialization
            bfrag[pg][h] = pk;
        }

    const short8_t* ef = (const short8_t*)wsE + (size_t)w * 2048;

    // ===== SINGLE SCREEN PASS: packed u32 top-3 (med3 insert); 2-deep PF =====
    unsigned p1[NPG], p2[NPG], p3[NPG];
    #pragma unroll
    for (int pg = 0; pg < NPG; ++pg) { p1[pg] = ~0u; p2[pg] = ~0u; p3[pg] = ~0u; }
    {
        short8_t A0a = ef[(0 * 64 + lane) * 2 + 0];
        short8_t A1a = ef[(0 * 64 + lane) * 2 + 1];
        short8_t A0b = ef[(1 * 64 + lane) * 2 + 0];
        short8_t A1b = ef[(1 * 64 + lane) * 2 + 1];
        #pragma unroll 1
        for (int ch = 0; ch < 16; ch += 2) {
            {   // even: consumes (A0a,A1a), prefetches ch+2
                int chn = ch + 2 < 16 ? ch + 2 : 15;
                short8_t N0 = ef[(chn * 64 + lane) * 2 + 0];
                short8_t N1 = ef[(chn * 64 + lane) * 2 + 1];
                int kbase = w * 256 + ch * 16 + 4 * (lane >> 4);
                f32x4 e2v = *(const f32x4*)(&sE2[kbase]);
                f32x4 e2bv;
                e2bv[0] = e2v[0] + BIAS; e2bv[1] = e2v[1] + BIAS;
                e2bv[2] = e2v[2] + BIAS; e2bv[3] = e2v[3] + BIAS;
                unsigned kb[4] = {(unsigned)kbase, (unsigned)kbase + 1u,
                                  (unsigned)kbase + 2u, (unsigned)kbase + 3u};
                #pragma unroll
                for (int pg = 0; pg < NPG; ++pg) {
                    f32x4 acc = __builtin_amdgcn_mfma_f32_16x16x32_bf16(A0a, bfrag[pg][0], e2bv, 0, 0, 0);
                    acc = __builtin_amdgcn_mfma_f32_16x16x32_bf16(A1a, bfrag[pg][1], acc, 0, 0, 0);
                    #pragma unroll
                    for (int j = 0; j < 4; ++j) {
                        unsigned t   = (__float_as_uint(acc[j]) & 0xFFFFFC00u) | kb[j];
                        unsigned np2 = umed3(p1[pg], p2[pg], t);
                        unsigned np3 = umed3(p2[pg], p3[pg], t);
                        p1[pg] = umin32(p1[pg], t);
                        p2[pg] = np2; p3[pg] = np3;
                    }
                }
                A0a = N0; A1a = N1;
            }
            {   // odd: consumes (A0b,A1b), prefetches ch+3
                int chn = ch + 3 < 16 ? ch + 3 : 15;
                short8_t N0 = ef[(chn * 64 + lane) * 2 + 0];
                short8_t N1 = ef[(chn * 64 + lane) * 2 + 1];
                int kbase = w * 256 + (ch + 1) * 16 + 4 * (lane >> 4);
                f32x4 e2v = *(const f32x4*)(&sE2[kbase]);
                f32x4 e2bv;
                e2bv[0] = e2v[0] + BIAS; e2bv[1] = e2v[1] + BIAS;
                e2bv[2] = e2v[2] + BIAS; e2bv[3] = e2v[3] + BIAS;
                unsigned kb[4] = {(unsigned)kbase, (unsigned)kbase + 1u,
                                  (unsigned)kbase + 2u, (unsigned)kbase + 3u};
                #pragma unroll
                for (int pg = 0; pg < NPG; ++pg) {
                    f32x4 acc = __builtin_amdgcn_mfma_f32_16x16x32_bf16(A0b, bfrag[pg][0], e2bv, 0, 0, 0);
                    acc = __builtin_amdgcn_mfma_f32_16x16x32_bf16(A1b, bfrag[pg][1], acc, 0, 0, 0);
                    #pragma unroll
                    for (int j = 0; j < 4; ++j) {
                        unsigned t   = (__float_as_uint(acc[j]) & 0xFFFFFC00u) | kb[j];
                        unsigned np2 = umed3(p1[pg], p2[pg], t);
                        unsigned np3 = umed3(p2[pg], p3[pg], t);
                        p1[pg] = umin32(p1[pg], t);
                        p2[pg] = np2; p3[pg] = np3;
                    }
                }
                A0b = N0; A1b = N1;
            }
        }
    }

    // per-pixel global packed min across lane-groups, then waves
    #pragma unroll
    for (int pg = 0; pg < NPG; ++pg) {
        unsigned g = p1[pg];
        g = umin32(g, (unsigned)__shfl_xor((int)g, 16, 64));
        g = umin32(g, (unsigned)__shfl_xor((int)g, 32, 64));
        if (lane < 16) sMinP[w][pg * 16 + lane] = g;
    }
    __syncthreads();                               // B2
    if (tid < PXB) {
        unsigned gp = umin32(umin32(sMinP[0][tid], sMinP[1][tid]),
                             umin32(sMinP[2][tid], sMinP[3][tid]));
        float m    = __uint_as_float(gp & 0xFFFFFC00u);
        float thrF = m + sBand[tid];
        sThrF[tid] = thrF;
        sThrP[tid] = (__float_as_uint(thrF) & 0xFFFFFC00u) | 1023u;
    }
    __syncthreads();                               // B3

    // ===== EMIT: single atomic per (lane,pg); flag on p3 in band =====
    #pragma unroll
    for (int pg = 0; pg < NPG; ++pg) {
        int px = pg * 16 + (lane & 15);
        unsigned thrp = sThrP[px];
        int n = (p1[pg] <= thrp) + (p2[pg] <= thrp) + (p3[pg] <= thrp);
        if (n) {
            int slot = atomicAdd(&sKcnt[px], n);
            if (slot < KDEPTH)                     sKbuf[px][slot]     = (unsigned short)(p1[pg] & 1023u);
            if (n >= 2 && slot + 1 < KDEPTH)       sKbuf[px][slot + 1] = (unsigned short)(p2[pg] & 1023u);
            if (n >= 3) {
                if (slot + 2 < KDEPTH)             sKbuf[px][slot + 2] = (unsigned short)(p3[pg] & 1023u);
                sPxFlag[px] = 1; sFlagAny = 1;     // lane may have dropped a 4th
            }
        }
    }
    __syncthreads();                               // B4

    // ===== RARE: flagged pixels -> full recollect (8 pg, 1-deep prefetch) =====
    if (sFlagAny) {
        if (tid < PXB && sPxFlag[tid]) sKcnt[tid] = 0;
        __syncthreads();
        float thrB[NPG];
        #pragma unroll
        for (int pg = 0; pg < NPG; ++pg) {
            int px = pg * 16 + (lane & 15);
            thrB[pg] = sPxFlag[px] ? sThrF[px] : -1e30f;
        }
        short8_t A0 = ef[lane * 2 + 0];
        short8_t A1 = ef[lane * 2 + 1];
        #pragma unroll 1
        for (int ch = 0; ch < 16; ++ch) {
            int chn = ch < 15 ? ch + 1 : 15;
            short8_t N0 = ef[(chn * 64 + lane) * 2 + 0];
            short8_t N1 = ef[(chn * 64 + lane) * 2 + 1];
            int kbase = w * 256 + ch * 16 + 4 * (lane >> 4);
            f32x4 e2v = *(const f32x4*)(&sE2[kbase]);
            f32x4 e2bv;
            e2bv[0] = e2v[0] + BIAS; e2bv[1] = e2v[1] + BIAS;
            e2bv[2] = e2v[2] + BIAS; e2bv[3] = e2v[3] + BIAS;
            #pragma unroll
            for (int pg = 0; pg < NPG; ++pg) {
                f32x4 acc = __builtin_amdgcn_mfma_f32_16x16x32_bf16(A0, bfrag[pg][0], e2bv, 0, 0, 0);
                acc = __builtin_amdgcn_mfma_f32_16x16x32_bf16(A1, bfrag[pg][1], acc, 0, 0, 0);
                #pragma unroll
                for (int j = 0; j < 4; ++j) {
                    if (acc[j] <= thrB[pg]) {
                        int pix  = pg * 16 + (lane & 15);
                        int slot = atomicAdd(&sKcnt[pix], 1);
                        if (slot < KDEPTH) sKbuf[pix][slot] = (unsigned short)(kbase + j);
                    }
                }
            }
            A0 = N0; A1 = N1;
        }
        __syncthreads();
    }

    // ===== EXACT EVAL: 2 threads/pixel; rawcnt==1 certified shortcut =====
    {
        const int px   = tid & (PXB - 1);
        const int half = tid >> 7;
        const float* zl = &sZf[px * ZSTRIDE];
        float zzv = sZZ[px];
        int rawcnt = sKcnt[px];
        if (rawcnt == 1) {
            if (half == 0) sBestPack[px] = packvk(-1e30f, (int)sKbuf[px][0]);
        } else if (rawcnt <= KDEPTH) {
            for (int s = half; s < rawcnt; s += 2) {
                int k = (int)sKbuf[px][s];
                float v = np_score(emb, k, zl, zzv, sE2[k]);
                atomicMin(&sBestPack[px], packvk(v, k));
            }
        } else {                                   // overflow safety net (~never)
            for (int k = half; k < NUM_EMB; k += 2) {
                float v = np_score(emb, k, zl, zzv, sE2[k]);
                atomicMin(&sBestPack[px], packvk(v, k));
            }
        }
    }
    __syncthreads();

    // ===== enc + epilogue (2 threads/pixel, 32 ch each, float4 gather) =====
    if (tid < PXB)
        enc_out[p0 + tid] = (float)(unsigned)(sBestPack[tid] & 0xFFFFFFFFull);
    {
        const int px   = tid & (PXB - 1);
        const int cg   = tid >> 7;
        int bestk = (int)(sBestPack[px] & 0xFFFFFFFFull);
        const float4* eq4 = (const float4*)(emb + bestk * EMB_DIM) + 8 * cg;
        const float* zl = &sZf[px * ZSTRIDE];
        float* op = zq_out + (size_t)b * (EMB_DIM * 4096) + hw0 + px;
        float ls = 0.f;
        #pragma unroll
        for (int j4 = 0; j4 < 8; ++j4) {
            float4 e4 = eq4[j4];
            int c = 32 * cg + j4 * 4;
            float d0 = e4.x - zl[c + 0];
            float d1 = e4.y - zl[c + 1];
            float d2 = e4.z - zl[c + 2];
            float d3 = e4.w - zl[c + 3];
            ls = fmaf(d0, d0, ls);
            ls = fmaf(d1, d1, ls);
            ls = fmaf(d2, d2, ls);
            ls = fmaf(d3, d3, ls);
            op[(size_t)(c + 0) * 4096] = e4.x;
            op[(size_t)(c + 1) * 4096] = e4.y;
            op[(size_t)(c + 2) * 4096] = e4.z;
            op[(size_t)(c + 3) * 4096] = e4.w;
        }
        #pragma unroll
        for (int off = 32; off > 0; off >>= 1) ls += __shfl_down(ls, off, 64);
        if (lane == 0) atomicAdd(&wsAcc[blockIdx.x & (NACC - 1)], ls);
    }
}

__global__ void vq_final_ws(const float* __restrict__ wsAcc,
                            float* __restrict__ loss_out) {
    int lane = threadIdx.x;                       // 64 threads
    float v = wsAcc[lane];
    #pragma unroll
    for (int off = 32; off > 0; off >>= 1) v += __shfl_down(v, off, 64);
    if (lane == 0) loss_out[0] = v * (1.25f / (float)ZQ_ELEMS);
}

__global__ void vq_final_direct(float* __restrict__ loss_out) {
    loss_out[0] = loss_out[0] * (1.25f / (float)ZQ_ELEMS);
}

// ---------- fallback (round-6 passing kernel) if d_ws is too small ----------
__global__ __launch_bounds__(256) void vq_nn_fb(const float* __restrict__ z_e,
                                                const float* __restrict__ emb,
                                                float* __restrict__ zq_out,
                                                float* __restrict__ enc_out,
                                                float* __restrict__ loss_acc) {
    #pragma clang fp contract(off)
    __shared__ float s_e2[NUM_EMB];
    int tid = threadIdx.x;
    for (int k = tid; k < NUM_EMB; k += 256) s_e2[k] = np_sumsq64(emb + k * EMB_DIM);
    __syncthreads();
    int p = blockIdx.x * 256 + tid;
    int b = p >> 12, hw = p & 4095;
    const float* zp = z_e + (size_t)b * (EMB_DIM * 4096) + hw;
    float z[EMB_DIM];
    #pragma unroll
    for (int c = 0; c < EMB_DIM; ++c) z[c] = zp[(size_t)c * 4096];
    float zz = np_sumsq64(z);
    float b1 = 3.4e38f; int i1 = 0;
    #pragma unroll 2
    for (int k = 0; k < NUM_EMB; ++k) {
        const float* ek = emb + k * EMB_DIM;
        float acc = 0.f;
        #pragma unroll
        for (int c = 0; c < EMB_DIM; ++c) acc = fmaf(ek[c], z[c], acc);
        float sc = (zz + s_e2[k]) - 2.0f * acc;
        bool lt = sc < b1; b1 = lt ? sc : b1; i1 = lt ? k : i1;
    }
    const float* eq = emb + i1 * EMB_DIM;
    float* op = zq_out + (size_t)b * (EMB_DIM * 4096) + hw;
    float ls = 0.f;
    #pragma unroll
    for (int c = 0; c < EMB_DIM; ++c) {
        float q = eq[c]; float d = q - z[c];
        ls = fmaf(d, d, ls);
        op[(size_t)c * 4096] = q;
    }
    enc_out[p] = (float)i1;
    #pragma unroll
    for (int off = 32; off > 0; off >>= 1) ls += __shfl_down(ls, off, 64);
    if ((tid & 63) == 0) atomicAdd(loss_acc, ls);
}

extern "C" void kernel_launch(void* const* d_in, const int* in_sizes, int n_in,
                              void* d_out, int out_size, void* d_ws, size_t ws_size,
                              hipStream_t stream) {
    const float* z_e = (const float*)d_in[0];
    const float* emb = (const float*)d_in[1];
    float* out = (float*)d_out;
    float* loss_out = out + ZQ_ELEMS;
    float* enc_out  = out + ZQ_ELEMS + 1;

    if (ws_size >= 140 * 1024) {
        short* wsE   = (short*)d_ws;                       // 128 KB frag-order
        float* wsE2  = (float*)((char*)d_ws + 131072);     // 4 KB
        float* wsAcc = (float*)((char*)d_ws + 135168);     // 256 B
        vq_prep<<<32, 256, 0, stream>>>(emb, wsE, wsE2, wsAcc);
        vq_mfma<<<NPIX / PXB, 256, 0, stream>>>(z_e, emb, wsE, wsE2, out, enc_out, wsAcc);
        vq_final_ws<<<1, 64, 0, stream>>>(wsAcc, loss_out);
    } else {
        hipMemsetAsync(loss_out, 0, 4, stream);
        vq_nn_fb<<<NPIX / 256, 256, 0, stream>>>(z_e, emb, out, enc_out, loss_out);
        vq_final_direct<<<1, 1, 0, stream>>>(loss_out);
    }
}